// Round 1
// 674.141 us; speedup vs baseline: 1.4018x; 1.4018x over previous
//
#include <hip/hip_runtime.h>

#define NUM_ITEM 500000
#define EMBED_DIM 64
#define PAD 16

// ---------------- padded-CSR pipeline ----------------

// Fused histogram + scatter: slot = old count. One pass over edges.
__global__ __launch_bounds__(256) void scatter_pad(
    const int* __restrict__ edge_src, const int* __restrict__ edge_dst,
    int num_edges, int* __restrict__ cnt, int* __restrict__ pad,
    int* __restrict__ ovf, int* __restrict__ ovf_n, int ovf_cap)
{
    int e = blockIdx.x * 256 + threadIdx.x;
    if (e >= num_edges) return;
    int d = edge_dst[e];
    int s = edge_src[e];
    int slot = atomicAdd(&cnt[d], 1);
    if (slot < PAD) {
        pad[(size_t)d * PAD + slot] = s;
    } else {
        int o = atomicAdd(ovf_n, 1);
        if (o < ovf_cap) { ovf[2 * o] = d; ovf[2 * o + 1] = s; }
    }
}

// One 64-lane wave per item; lane = embedding dim.
// cnt + 8 indices loaded speculatively in parallel (pad base is item*PAD,
// known before cnt arrives) -> 8 independent row gathers. Dependent chain
// drops from ~2*cnt latencies to ~2 latencies total for 98% of items.
__global__ __launch_bounds__(256) void gather_pad(
    const float* __restrict__ user_embed, const int* __restrict__ pad,
    const int* __restrict__ cnt, float* __restrict__ out, int n_items)
{
    int item = blockIdx.x * 4 + (threadIdx.x >> 6);
    int lane = threadIdx.x & 63;
    if (item >= n_items) return;

    const int* p = pad + (size_t)item * PAD;
    int c = cnt[item];                       // wave-uniform
    int4 i0 = *(const int4*)p;               // speculative, independent of c
    int4 i1 = *(const int4*)(p + 4);
    int sidx[8] = {i0.x, i0.y, i0.z, i0.w, i1.x, i1.y, i1.z, i1.w};

    float sum = 0.f;
#pragma unroll
    for (int e = 0; e < 8; ++e) {
        int s = (e < c) ? sidx[e] : 0;       // clamp -> safe address, L1-hot row 0
        float v = user_embed[(size_t)s * EMBED_DIM + lane];
        sum += (e < c) ? v : 0.f;
    }
    int cc = (c < PAD) ? c : PAD;
    for (int e = 8; e < cc; ++e) {           // rare tail (P ~ 2%)
        int s = p[e];
        sum += user_embed[(size_t)s * EMBED_DIM + lane];
    }
    float denom = (c > 0) ? (float)c : 1.0f;
    out[(size_t)item * EMBED_DIM + lane] = sum / denom;
}

// Exact handling of the (astronomically rare) cnt > PAD items.
// Runs after gather_pad: out already holds sum(first PAD)/cnt; add row/cnt
// for each overflow edge. With ovf_n == 0 this is a ~3 us no-op.
__global__ __launch_bounds__(256) void fixup_overflow(
    const float* __restrict__ user_embed, const int* __restrict__ ovf,
    const int* __restrict__ ovf_n, const int* __restrict__ cnt,
    float* __restrict__ out, int ovf_cap)
{
    int n = *ovf_n;
    if (n > ovf_cap) n = ovf_cap;
    int wave = blockIdx.x * 4 + (threadIdx.x >> 6);
    int lane = threadIdx.x & 63;
    int nwaves = gridDim.x * 4;
    for (int i = wave; i < n; i += nwaves) {
        int d = ovf[2 * i];
        int s = ovf[2 * i + 1];
        float v = user_embed[(size_t)s * EMBED_DIM + lane] / (float)cnt[d];
        atomicAdd(&out[(size_t)d * EMBED_DIM + lane], v);
    }
}

// ---------------- tier-2: exact CSR pipeline (previous best) ----------------

__global__ __launch_bounds__(256) void histogram_dst(
    const int* __restrict__ edge_dst, int num_edges, int* __restrict__ counts)
{
    int e = blockIdx.x * blockDim.x + threadIdx.x;
    if (e >= num_edges) return;
    atomicAdd(&counts[edge_dst[e]], 1);
}

__global__ __launch_bounds__(256) void block_sums(
    const int* __restrict__ counts, int n, int* __restrict__ partials)
{
    __shared__ int red[256];
    int i = blockIdx.x * 256 + threadIdx.x;
    red[threadIdx.x] = (i < n) ? counts[i] : 0;
    __syncthreads();
    for (int s = 128; s > 0; s >>= 1) {
        if (threadIdx.x < (unsigned)s) red[threadIdx.x] += red[threadIdx.x + s];
        __syncthreads();
    }
    if (threadIdx.x == 0) partials[blockIdx.x] = red[0];
}

__global__ __launch_bounds__(256) void scan_partials(int* __restrict__ partials, int nb)
{
    __shared__ int tmp[256];
    __shared__ int carry_s;
    if (threadIdx.x == 0) carry_s = 0;
    __syncthreads();
    for (int base = 0; base < nb; base += 256) {
        int i = base + threadIdx.x;
        int v = (i < nb) ? partials[i] : 0;
        tmp[threadIdx.x] = v;
        __syncthreads();
        for (int off = 1; off < 256; off <<= 1) {
            int t = (threadIdx.x >= (unsigned)off) ? tmp[threadIdx.x - off] : 0;
            __syncthreads();
            tmp[threadIdx.x] += t;
            __syncthreads();
        }
        int incl = tmp[threadIdx.x];
        int c = carry_s;
        if (i < nb) partials[i] = incl - v + c;
        __syncthreads();
        if (threadIdx.x == 255) carry_s = c + tmp[255];
        __syncthreads();
    }
}

__global__ __launch_bounds__(256) void make_offsets(
    const int* __restrict__ counts, const int* __restrict__ partials, int n,
    int* __restrict__ offsets, int* __restrict__ cursor)
{
    __shared__ int tmp[256];
    int i = blockIdx.x * 256 + threadIdx.x;
    int v = (i < n) ? counts[i] : 0;
    tmp[threadIdx.x] = v;
    __syncthreads();
    for (int off = 1; off < 256; off <<= 1) {
        int t = (threadIdx.x >= (unsigned)off) ? tmp[threadIdx.x - off] : 0;
        __syncthreads();
        tmp[threadIdx.x] += t;
        __syncthreads();
    }
    int excl = tmp[threadIdx.x] - v + partials[blockIdx.x];
    if (i < n) { offsets[i] = excl; cursor[i] = excl; }
}

__global__ __launch_bounds__(256) void scatter_csr(
    const int* __restrict__ edge_src, const int* __restrict__ edge_dst,
    int num_edges, int* __restrict__ cursor, int* __restrict__ csr_src)
{
    int e = blockIdx.x * blockDim.x + threadIdx.x;
    if (e >= num_edges) return;
    int d = edge_dst[e];
    int pos = atomicAdd(&cursor[d], 1);
    csr_src[pos] = edge_src[e];
}

__global__ __launch_bounds__(256) void gather_mean(
    const float* __restrict__ user_embed, const int* __restrict__ csr_src,
    const int* __restrict__ offsets, const int* __restrict__ counts,
    float* __restrict__ out, int n_items)
{
    int item = blockIdx.x * 4 + (threadIdx.x >> 6);
    int lane = threadIdx.x & 63;
    if (item >= n_items) return;
    int off = offsets[item];
    int cnt = counts[item];
    float sum = 0.f;
    for (int e = 0; e < cnt; ++e) {
        int s = csr_src[off + e];
        sum += user_embed[(size_t)s * EMBED_DIM + lane];
    }
    float denom = (cnt > 0) ? (float)cnt : 1.0f;
    out[(size_t)item * EMBED_DIM + lane] = sum / denom;
}

// ---------------- tier-3: atomic fallback ----------------

__global__ __launch_bounds__(256) void scatter_mean_accum(
    const float* __restrict__ user_embed,
    const int* __restrict__ edge_src,
    const int* __restrict__ edge_dst,
    float* __restrict__ sums, float* __restrict__ counts, int num_edges)
{
    const int edge = blockIdx.x * (blockDim.x >> 6) + (threadIdx.x >> 6);
    const int lane = threadIdx.x & 63;
    if (edge >= num_edges) return;
    const int s = edge_src[edge];
    const int d = edge_dst[edge];
    atomicAdd(&sums[(size_t)d * EMBED_DIM + lane],
              user_embed[(size_t)s * EMBED_DIM + lane]);
    if (lane == 0) atomicAdd(&counts[d], 1.0f);
}

__global__ __launch_bounds__(256) void divide_by_count(
    float* __restrict__ out, const float* __restrict__ counts, int n)
{
    const int idx = blockIdx.x * blockDim.x + threadIdx.x;
    if (idx >= n) return;
    out[idx] = out[idx] / fmaxf(counts[idx >> 6], 1.0f);
}

// ---------------- launcher ----------------

extern "C" void kernel_launch(void* const* d_in, const int* in_sizes, int n_in,
                              void* d_out, int out_size, void* d_ws, size_t ws_size,
                              hipStream_t stream)
{
    const float* user_embed = (const float*)d_in[0];
    const int* edge_src = (const int*)d_in[2];
    const int* edge_dst = (const int*)d_in[3];
    const int num_edges = in_sizes[2];
    float* out = (float*)d_out;

    const int eb = (num_edges + 255) / 256;

    // ---- tier 1: padded CSR ----
    // ws layout: ovf_n(64B) | cnt (2MB) | pad (NUM_ITEM*PAD*4 = 32MB) | ovf (2*cap*4)
    const size_t hdr_b = 64;
    const size_t cnt_b = (size_t)NUM_ITEM * 4;
    const size_t pad_b = (size_t)NUM_ITEM * PAD * 4;
    const size_t fixed = hdr_b + cnt_b + pad_b;
    long long cap_ll = ((long long)ws_size - (long long)fixed) / 8;
    if (cap_ll > num_edges) cap_ll = num_edges;
    const int min_cap = (num_edges < 4096) ? num_edges : 4096;

    if (cap_ll >= min_cap) {
        char* ws = (char*)d_ws;
        int* ovf_n = (int*)ws;
        int* cnt   = (int*)(ws + hdr_b);
        int* pad   = (int*)(ws + hdr_b + cnt_b);
        int* ovf   = (int*)(ws + fixed);
        const int ovf_cap = (int)cap_ll;

        hipMemsetAsync(d_ws, 0, hdr_b + cnt_b, stream);   // ovf_n + cnt
        scatter_pad<<<eb, 256, 0, stream>>>(edge_src, edge_dst, num_edges,
                                            cnt, pad, ovf, ovf_n, ovf_cap);
        gather_pad<<<(NUM_ITEM + 3) / 4, 256, 0, stream>>>(
            user_embed, pad, cnt, out, NUM_ITEM);
        fixup_overflow<<<64, 256, 0, stream>>>(user_embed, ovf, ovf_n, cnt,
                                               out, ovf_cap);
        return;
    }

    // ---- tier 2: exact CSR pipeline ----
    const int NB = (NUM_ITEM + 255) / 256;
    const size_t counts_b   = (size_t)NUM_ITEM * 4;
    const size_t offsets_b  = (size_t)NUM_ITEM * 4;
    const size_t cursor_b   = (size_t)NUM_ITEM * 4;
    const size_t partials_b = 2048 * 4;
    const size_t csr_b      = (size_t)num_edges * 4;
    const size_t needed = counts_b + offsets_b + cursor_b + partials_b + csr_b;

    if (ws_size >= needed) {
        char* ws = (char*)d_ws;
        int* counts   = (int*)ws;                         ws += counts_b;
        int* offsets  = (int*)ws;                         ws += offsets_b;
        int* cursor   = (int*)ws;                         ws += cursor_b;
        int* partials = (int*)ws;                         ws += partials_b;
        int* csr_src  = (int*)ws;

        hipMemsetAsync(counts, 0, counts_b, stream);
        histogram_dst<<<eb, 256, 0, stream>>>(edge_dst, num_edges, counts);
        block_sums<<<NB, 256, 0, stream>>>(counts, NUM_ITEM, partials);
        scan_partials<<<1, 256, 0, stream>>>(partials, NB);
        make_offsets<<<NB, 256, 0, stream>>>(counts, partials, NUM_ITEM, offsets, cursor);
        scatter_csr<<<eb, 256, 0, stream>>>(edge_src, edge_dst, num_edges, cursor, csr_src);
        gather_mean<<<(NUM_ITEM + 3) / 4, 256, 0, stream>>>(
            user_embed, csr_src, offsets, counts, out, NUM_ITEM);
    } else {
        // ---- tier 3: atomic scatter ----
        float* counts = (float*)d_ws;
        hipMemsetAsync(d_out, 0, (size_t)NUM_ITEM * EMBED_DIM * sizeof(float), stream);
        hipMemsetAsync(d_ws, 0, (size_t)NUM_ITEM * sizeof(float), stream);
        const int blocks = (num_edges + 3) / 4;
        scatter_mean_accum<<<blocks, 256, 0, stream>>>(
            user_embed, edge_src, edge_dst, out, counts, num_edges);
        const int n = NUM_ITEM * EMBED_DIM;
        divide_by_count<<<(n + 255) / 256, 256, 0, stream>>>(out, counts, n);
    }
}